// Round 6
// baseline (350.380 us; speedup 1.0000x reference)
//
#include <hip/hip_runtime.h>
#include <hip/hip_bf16.h>

#define NHEAD 8
#define DK 64
#define DMODEL 512
#define LSEQ 1000
#define TI 64
#define TJ 64
#define NJT 16

typedef __attribute__((ext_vector_type(8))) short bf16x8;
typedef __attribute__((ext_vector_type(4))) float f32x4;

__device__ inline short f2bf(float f) {
    __hip_bfloat16 h = __float2bfloat16(f);
    return *reinterpret_cast<short*>(&h);
}
__device__ inline float bf2f(short s) {
    unsigned int u = ((unsigned int)(unsigned short)s) << 16;
    return __uint_as_float(u);
}
__device__ inline void gload_lds16(const void* g, void* l) {
    __builtin_amdgcn_global_load_lds(
        (const __attribute__((address_space(1))) unsigned int*)g,
        (__attribute__((address_space(3))) unsigned int*)l, 16, 0, 0);
}

// ---------------- convert weights/E to bf16 (Wq,bq folded /8; E folded x8) ----------------
__global__ __launch_bounds__(256) void convert_kernel(
    const float* __restrict__ Wq, const float* __restrict__ Wk, const float* __restrict__ Wv,
    const float* __restrict__ Wo, const float* __restrict__ E,
    short* __restrict__ Wqkv_bf, short* __restrict__ Wo_bf, short* __restrict__ E_bf)
{
    int qd = blockIdx.x * 256 + threadIdx.x;
    if (qd < 196608) {
        int flat = qd * 4;
        int row = flat >> 9, col = flat & 511;
        int proj = row >> 9, rrow = row & 511;
        const float* src = proj == 0 ? Wq : (proj == 1 ? Wk : Wv);
        float sc = proj == 0 ? 0.125f : 1.0f;
        float4 x = *(const float4*)&src[(size_t)rrow * 512 + col];
        short t[4] = { f2bf(x.x * sc), f2bf(x.y * sc), f2bf(x.z * sc), f2bf(x.w * sc) };
        *(uint2*)&Wqkv_bf[flat] = *(uint2*)t;
    } else if (qd < 262144) {
        int flat = (qd - 196608) * 4;
        float4 x = *(const float4*)&Wo[flat];
        short t[4] = { f2bf(x.x), f2bf(x.y), f2bf(x.z), f2bf(x.w) };
        *(uint2*)&Wo_bf[flat] = *(uint2*)t;
    } else if (qd < 294128) {
        int flat = (qd - 262144) * 4;
        float4 x = *(const float4*)&E[flat];
        short t[4] = { f2bf(x.x * 8.f), f2bf(x.y * 8.f), f2bf(x.z * 8.f), f2bf(x.w * 8.f) };
        *(uint2*)&E_bf[flat] = *(uint2*)t;
    }
}

// ---------------- LayerNorm -> bf16 ----------------
__global__ __launch_bounds__(256) void ln_kernel(
    const float* __restrict__ x, const float* __restrict__ gamma,
    const float* __restrict__ beta, short* __restrict__ xn)
{
    int row = blockIdx.x;
    int tid = threadIdx.x;
    const float2* xr = (const float2*)(x + (size_t)row * DMODEL);
    float2 v = xr[tid];
    float s  = v.x + v.y;
    float ss = v.x * v.x + v.y * v.y;
#pragma unroll
    for (int o = 32; o > 0; o >>= 1) {
        s  += __shfl_down(s, o, 64);
        ss += __shfl_down(ss, o, 64);
    }
    __shared__ float red[8];
    int wid = tid >> 6;
    if ((tid & 63) == 0) { red[wid * 2] = s; red[wid * 2 + 1] = ss; }
    __syncthreads();
    s  = red[0] + red[2] + red[4] + red[6];
    ss = red[1] + red[3] + red[5] + red[7];
    float mu  = s * (1.0f / (float)DMODEL);
    float var = ss * (1.0f / (float)DMODEL) - mu * mu;
    float inv = rsqrtf(var + 1e-5f);
    float2 g  = ((const float2*)gamma)[tid];
    float2 bb = ((const float2*)beta)[tid];
    short o2[2];
    o2[0] = f2bf((v.x - mu) * inv * g.x + bb.x);
    o2[1] = f2bf((v.y - mu) * inv * g.y + bb.y);
    *(unsigned int*)&xn[(size_t)row * DMODEL + tid * 2] = *(unsigned int*)o2;
}

// ---------------- bf16 MFMA GEMM (m97 structure: 128x128 tile, BK=32) ----------------
template<int MODE>
__global__ __launch_bounds__(256) void gemm_bf16(
    const short* __restrict__ A, const short* __restrict__ W,
    const float* __restrict__ b0, const float* __restrict__ b1, const float* __restrict__ b2,
    short* __restrict__ Oq, short* __restrict__ Ok, short* __restrict__ Ov,
    float* __restrict__ Of, const float* __restrict__ resid)
{
    __shared__ short As[128 * 32];
    __shared__ short Bs[128 * 32];
    const int K = 512;
    const int tid = threadIdx.x;
    const int lane = tid & 63, w = tid >> 6;
    const int m0 = blockIdx.y * 128, n0 = blockIdx.x * 128;
    const int wr = w >> 1, wc = w & 1;

    const int srow = (lane >> 2);
    const int scol = (lane & 3) * 8;
    int ga0 = m0 + (w * 2 + 0) * 16 + srow; if (ga0 > 7999) ga0 = 7999;
    int ga1 = m0 + (w * 2 + 1) * 16 + srow; if (ga1 > 7999) ga1 = 7999;
    const int gb0 = n0 + (w * 2 + 0) * 16 + srow;
    const int gb1 = n0 + (w * 2 + 1) * 16 + srow;

    f32x4 acc[4][4];
#pragma unroll
    for (int i = 0; i < 4; ++i)
#pragma unroll
        for (int j = 0; j < 4; ++j) acc[i][j] = (f32x4){0.f, 0.f, 0.f, 0.f};

    for (int k0 = 0; k0 < K; k0 += 32) {
        __syncthreads();
        gload_lds16(&A[(size_t)ga0 * K + k0 + scol], &As[(w * 2 + 0) * 512]);
        gload_lds16(&A[(size_t)ga1 * K + k0 + scol], &As[(w * 2 + 1) * 512]);
        gload_lds16(&W[(size_t)gb0 * K + k0 + scol], &Bs[(w * 2 + 0) * 512]);
        gload_lds16(&W[(size_t)gb1 * K + k0 + scol], &Bs[(w * 2 + 1) * 512]);
        __syncthreads();

        bf16x8 af[4], bf[4];
#pragma unroll
        for (int fi = 0; fi < 4; ++fi)
            af[fi] = *(bf16x8*)&As[(wr * 64 + fi * 16 + (lane & 15)) * 32 + (lane >> 4) * 8];
#pragma unroll
        for (int fj = 0; fj < 4; ++fj)
            bf[fj] = *(bf16x8*)&Bs[(wc * 64 + fj * 16 + (lane & 15)) * 32 + (lane >> 4) * 8];
#pragma unroll
        for (int fi = 0; fi < 4; ++fi)
#pragma unroll
            for (int fj = 0; fj < 4; ++fj)
                acc[fi][fj] = __builtin_amdgcn_mfma_f32_16x16x32_bf16(af[fi], bf[fj], acc[fi][fj], 0, 0, 0);
    }

#pragma unroll
    for (int fi = 0; fi < 4; ++fi) {
#pragma unroll
        for (int fj = 0; fj < 4; ++fj) {
#pragma unroll
            for (int r = 0; r < 4; ++r) {
                int m = m0 + wr * 64 + fi * 16 + (lane >> 4) * 4 + r;
                if (m >= 8000) continue;
                int n = n0 + wc * 64 + fj * 16 + (lane & 15);
                float val = acc[fi][fj][r];
                if (MODE == 0) {
                    int proj = n >> 9, rem = n & 511;
                    int h = rem >> 6, d = rem & 63;
                    float bias = proj == 0 ? b0[rem] * 0.125f : (proj == 1 ? b1[rem] : b2[rem]);
                    short* O = proj == 0 ? Oq : (proj == 1 ? Ok : Ov);
                    int bb = m / 1000, ii = m - bb * 1000;
                    O[((size_t)(bb * NHEAD + h) * LSEQ + ii) * DK + d] = f2bf(val + bias);
                } else {
                    Of[(size_t)m * DMODEL + n] = val + b0[n] + resid[(size_t)m * DMODEL + n];
                }
            }
        }
    }
}

// ---------------- Flash attention, bf16 MFMA, bf16 I/O ----------------
// LDS diet: 45056 B -> 3 blocks/CU. E fragments loaded direct from L2.
// QsPl: Q staging, reused as P (probabilities) after fragments hoisted.
__global__ __launch_bounds__(256, 3) void attn_mfma(
    const short* __restrict__ q, const short* __restrict__ k,
    const short* __restrict__ v, const short* __restrict__ E,
    short* __restrict__ ctx)
{
    __shared__ short QsPl[TI][72];   // Q tile, then P tile (wave-private rows)
    __shared__ short Kt[TJ][72];
    __shared__ short Vt[DK][72];     // V transposed: Vt[d][j]
    __shared__ short Pp[TI][136];    // pos-score window (wave-private rows)

    const int it = blockIdx.x, h = blockIdx.y, b = blockIdx.z;
    const int i0 = it * TI;
    const int tid = threadIdx.x;
    const int lane = tid & 63, w = tid >> 6;
    const int g = lane >> 4, c = lane & 15;

    const size_t base = (size_t)(b * NHEAD + h) * LSEQ * DK;

    // stage Q tile (bf16 direct copy, row-clamped)
#pragma unroll
    for (int rep = 0; rep < 2; ++rep) {
        int id = tid + rep * 256;
        int row = id >> 3, c0 = (id & 7) * 8;
        int gr = i0 + row; if (gr > LSEQ - 1) gr = LSEQ - 1;
        *(int4*)&QsPl[row][c0] = *(const int4*)&q[base + (size_t)gr * DK + c0];
    }
    __syncthreads();

    bf16x8 Aq0 = *(bf16x8*)&QsPl[w * 16 + c][g * 8];
    bf16x8 Aq1 = *(bf16x8*)&QsPl[w * 16 + c][32 + g * 8];

    float mrow[4], lrow[4];
    f32x4 acc[4];
#pragma unroll
    for (int r = 0; r < 4; ++r) { mrow[r] = -1e30f; lrow[r] = 0.f; }
#pragma unroll
    for (int fd = 0; fd < 4; ++fd) acc[fd] = (f32x4){0.f, 0.f, 0.f, 0.f};

    for (int jt = 0; jt < NJT; ++jt) {
        const int j0 = jt * TJ;
        const int d0 = j0 - i0 + (LSEQ - 1) - 63;
        __syncthreads();   // prev iteration LDS reads done; QsPl free at jt=0

        // ---- stage K tile ----
#pragma unroll
        for (int rep = 0; rep < 2; ++rep) {
            int id = tid + rep * 256;
            int row = id >> 3, c0 = (id & 7) * 8;
            int gr = j0 + row; if (gr > LSEQ - 1) gr = LSEQ - 1;
            *(int4*)&Kt[row][c0] = *(const int4*)&k[base + (size_t)gr * DK + c0];
        }
        // ---- stage V transposed, conflict-free writes ----
        // id bits: [3:0]=j_lo, [7:4]=dquad, [9:8]=j_hi; 16-lane group writes
        // 16 consecutive j of one row (8 dwords, no bank conflict).
#pragma unroll
        for (int rep = 0; rep < 4; ++rep) {
            int id = tid + rep * 256;
            int j = ((id >> 8) << 4) | (id & 15);
            int dq = ((id >> 4) & 15) * 4;
            int gr = j0 + j; if (gr > LSEQ - 1) gr = LSEQ - 1;
            short t[4];
            *(int2*)t = *(const int2*)&v[base + (size_t)gr * DK + dq];
            Vt[dq + 0][j] = t[0];
            Vt[dq + 1][j] = t[1];
            Vt[dq + 2][j] = t[2];
            Vt[dq + 3][j] = t[3];
        }
        // ---- E window B-fragments direct from global (L2-resident) ----
        bf16x8 ef[8][2];
#pragma unroll
        for (int fd = 0; fd < 8; ++fd) {
            int dd = d0 + fd * 16 + c;
            if (dd < 0) dd = 0;
            if (dd > 2 * LSEQ - 2) dd = 2 * LSEQ - 2;
            const short* erow = E + (size_t)dd * DK;
            ef[fd][0] = *(const bf16x8*)&erow[g * 8];
            ef[fd][1] = *(const bf16x8*)&erow[32 + g * 8];
        }
        __syncthreads();

        // ---- pos scores: Pp = Aq @ E_window^T (wave-private rows) ----
#pragma unroll
        for (int fd = 0; fd < 8; ++fd) {
            f32x4 pa = (f32x4){0.f, 0.f, 0.f, 0.f};
            pa = __builtin_amdgcn_mfma_f32_16x16x32_bf16(Aq0, ef[fd][0], pa, 0, 0, 0);
            pa = __builtin_amdgcn_mfma_f32_16x16x32_bf16(Aq1, ef[fd][1], pa, 0, 0, 0);
#pragma unroll
            for (int r = 0; r < 4; ++r)
                Pp[w * 16 + g * 4 + r][fd * 16 + c] = f2bf(pa[r]);
        }

        // ---- QK^T ----
        f32x4 sf[4];
#pragma unroll
        for (int fj = 0; fj < 4; ++fj) {
            f32x4 s4 = (f32x4){0.f, 0.f, 0.f, 0.f};
            bf16x8 k0v = *(bf16x8*)&Kt[fj * 16 + c][g * 8];
            bf16x8 k1v = *(bf16x8*)&Kt[fj * 16 + c][32 + g * 8];
            s4 = __builtin_amdgcn_mfma_f32_16x16x32_bf16(Aq0, k0v, s4, 0, 0, 0);
            s4 = __builtin_amdgcn_mfma_f32_16x16x32_bf16(Aq1, k1v, s4, 0, 0, 0);
            sf[fj] = s4;
        }

        // ---- add pos (diag gather), mask, online softmax ----
        float sv[4][4], pm[4];
#pragma unroll
        for (int r = 0; r < 4; ++r) pm[r] = -1e30f;
#pragma unroll
        for (int fj = 0; fj < 4; ++fj) {
            int jl = fj * 16 + c;
            bool valid = (j0 + jl) < LSEQ;
#pragma unroll
            for (int r = 0; r < 4; ++r) {
                int ilt = w * 16 + g * 4 + r;
                int d = jl - ilt + 63;
                float x = sf[fj][r] + bf2f(Pp[ilt][d]);
                if (!valid) x = -1e30f;
                sv[fj][r] = x;
                pm[r] = fmaxf(pm[r], x);
            }
        }
#pragma unroll
        for (int r = 0; r < 4; ++r) {
            float vv = pm[r];
            vv = fmaxf(vv, __shfl_xor(vv, 1));
            vv = fmaxf(vv, __shfl_xor(vv, 2));
            vv = fmaxf(vv, __shfl_xor(vv, 4));
            vv = fmaxf(vv, __shfl_xor(vv, 8));
            pm[r] = vv;
        }
        float psum[4];
#pragma unroll
        for (int r = 0; r < 4; ++r) {
            float mn = fmaxf(mrow[r], pm[r]);
            float sc = __expf(mrow[r] - mn);
            mrow[r] = mn;
            lrow[r] *= sc;
#pragma unroll
            for (int fd = 0; fd < 4; ++fd) acc[fd][r] *= sc;
            psum[r] = 0.f;
        }
#pragma unroll
        for (int fj = 0; fj < 4; ++fj) {
            int jl = fj * 16 + c;
#pragma unroll
            for (int r = 0; r < 4; ++r) {
                float p = __expf(sv[fj][r] - mrow[r]);
                psum[r] += p;
                QsPl[w * 16 + g * 4 + r][jl] = f2bf(p);
            }
        }
#pragma unroll
        for (int r = 0; r < 4; ++r) {
            float vv = psum[r];
            vv += __shfl_xor(vv, 1);
            vv += __shfl_xor(vv, 2);
            vv += __shfl_xor(vv, 4);
            vv += __shfl_xor(vv, 8);
            lrow[r] += vv;
        }

        // ---- PV ----
#pragma unroll
        for (int ks = 0; ks < 2; ++ks) {
            bf16x8 ap = *(bf16x8*)&QsPl[w * 16 + c][ks * 32 + g * 8];
#pragma unroll
            for (int fd = 0; fd < 4; ++fd) {
                bf16x8 bv2 = *(bf16x8*)&Vt[fd * 16 + c][ks * 32 + g * 8];
                acc[fd] = __builtin_amdgcn_mfma_f32_16x16x32_bf16(ap, bv2, acc[fd], 0, 0, 0);
            }
        }
    }

    // ---- epilogue: normalize + store ctx bf16 (B, L, D) ----
#pragma unroll
    for (int r = 0; r < 4; ++r) {
        int ig = i0 + w * 16 + g * 4 + r;
        if (ig < LSEQ) {
            float inv = 1.0f / lrow[r];
#pragma unroll
            for (int fd = 0; fd < 4; ++fd)
                ctx[((size_t)(b * LSEQ + ig)) * DMODEL + h * DK + fd * 16 + c] =
                    f2bf(acc[fd][r] * inv);
        }
    }
}

extern "C" void kernel_launch(void* const* d_in, const int* in_sizes, int n_in,
                              void* d_out, int out_size, void* d_ws, size_t ws_size,
                              hipStream_t stream)
{
    const float* x     = (const float*)d_in[0];
    const float* Wq    = (const float*)d_in[1];
    const float* bq    = (const float*)d_in[2];
    const float* Wk    = (const float*)d_in[3];
    const float* bk    = (const float*)d_in[4];
    const float* Wv    = (const float*)d_in[5];
    const float* bv    = (const float*)d_in[6];
    const float* Wo    = (const float*)d_in[7];
    const float* bo    = (const float*)d_in[8];
    const float* E     = (const float*)d_in[9];
    const float* gamma = (const float*)d_in[10];
    const float* beta  = (const float*)d_in[11];
    float* out = (float*)d_out;

    const size_t nTok = 8 * LSEQ;               // 8000
    const size_t nBLD = nTok * DMODEL;          // 4,096,000 elems
    short* xn_bf   = (short*)d_ws;
    short* qb      = xn_bf + nBLD;
    short* kb      = qb + nBLD;
    short* vb      = kb + nBLD;
    short* ctx_bf  = vb + nBLD;
    short* Wqkv_bf = ctx_bf + nBLD;
    short* Wo_bf   = Wqkv_bf + 1536 * 512;
    short* E_bf    = Wo_bf + 512 * 512;

    convert_kernel<<<1149, 256, 0, stream>>>(Wq, Wk, Wv, Wo, E, Wqkv_bf, Wo_bf, E_bf);
    ln_kernel<<<(int)nTok, 256, 0, stream>>>(x, gamma, beta, xn_bf);
    gemm_bf16<0><<<dim3(12, 63), 256, 0, stream>>>(
        xn_bf, Wqkv_bf, bq, bk, bv, qb, kb, vb, nullptr, nullptr);
    attn_mfma<<<dim3((LSEQ + TI - 1) / TI, NHEAD, 8), 256, 0, stream>>>(
        qb, kb, vb, E_bf, ctx_bf);
    gemm_bf16<1><<<dim3(4, 63), 256, 0, stream>>>(
        ctx_bf, Wo_bf, bo, nullptr, nullptr, nullptr, nullptr, nullptr, out, x);
}

// Round 8
// 269.126 us; speedup vs baseline: 1.3019x; 1.3019x over previous
//
#include <hip/hip_runtime.h>
#include <hip/hip_bf16.h>

#define NHEAD 8
#define DK 64
#define DMODEL 512
#define LSEQ 1000
#define TI 64
#define TJ 64
#define NJT 16

typedef __attribute__((ext_vector_type(8))) short bf16x8;
typedef __attribute__((ext_vector_type(4))) float f32x4;

__device__ inline short f2bf(float f) {
    __hip_bfloat16 h = __float2bfloat16(f);
    return *reinterpret_cast<short*>(&h);
}
__device__ inline float bf2f(short s) {
    unsigned int u = ((unsigned int)(unsigned short)s) << 16;
    return __uint_as_float(u);
}
__device__ inline void gload_lds16(const void* g, void* l) {
    __builtin_amdgcn_global_load_lds(
        (const __attribute__((address_space(1))) unsigned int*)g,
        (__attribute__((address_space(3))) unsigned int*)l, 16, 0, 0);
}

// ---------------- convert weights/E to bf16 (Wq,bq folded /8; E folded x8) ----------------
__global__ __launch_bounds__(256) void convert_kernel(
    const float* __restrict__ Wq, const float* __restrict__ Wk, const float* __restrict__ Wv,
    const float* __restrict__ Wo, const float* __restrict__ E,
    short* __restrict__ Wqkv_bf, short* __restrict__ Wo_bf, short* __restrict__ E_bf)
{
    int qd = blockIdx.x * 256 + threadIdx.x;
    if (qd < 196608) {
        int flat = qd * 4;
        int row = flat >> 9, col = flat & 511;
        int proj = row >> 9, rrow = row & 511;
        const float* src = proj == 0 ? Wq : (proj == 1 ? Wk : Wv);
        float sc = proj == 0 ? 0.125f : 1.0f;
        float4 x = *(const float4*)&src[(size_t)rrow * 512 + col];
        short t[4] = { f2bf(x.x * sc), f2bf(x.y * sc), f2bf(x.z * sc), f2bf(x.w * sc) };
        *(uint2*)&Wqkv_bf[flat] = *(uint2*)t;
    } else if (qd < 262144) {
        int flat = (qd - 196608) * 4;
        float4 x = *(const float4*)&Wo[flat];
        short t[4] = { f2bf(x.x), f2bf(x.y), f2bf(x.z), f2bf(x.w) };
        *(uint2*)&Wo_bf[flat] = *(uint2*)t;
    } else if (qd < 294128) {
        int flat = (qd - 262144) * 4;
        float4 x = *(const float4*)&E[flat];
        short t[4] = { f2bf(x.x * 8.f), f2bf(x.y * 8.f), f2bf(x.z * 8.f), f2bf(x.w * 8.f) };
        *(uint2*)&E_bf[flat] = *(uint2*)t;
    }
}

// ---------------- LayerNorm -> bf16 ----------------
__global__ __launch_bounds__(256) void ln_kernel(
    const float* __restrict__ x, const float* __restrict__ gamma,
    const float* __restrict__ beta, short* __restrict__ xn)
{
    int row = blockIdx.x;
    int tid = threadIdx.x;
    const float2* xr = (const float2*)(x + (size_t)row * DMODEL);
    float2 v = xr[tid];
    float s  = v.x + v.y;
    float ss = v.x * v.x + v.y * v.y;
#pragma unroll
    for (int o = 32; o > 0; o >>= 1) {
        s  += __shfl_down(s, o, 64);
        ss += __shfl_down(ss, o, 64);
    }
    __shared__ float red[8];
    int wid = tid >> 6;
    if ((tid & 63) == 0) { red[wid * 2] = s; red[wid * 2 + 1] = ss; }
    __syncthreads();
    s  = red[0] + red[2] + red[4] + red[6];
    ss = red[1] + red[3] + red[5] + red[7];
    float mu  = s * (1.0f / (float)DMODEL);
    float var = ss * (1.0f / (float)DMODEL) - mu * mu;
    float inv = rsqrtf(var + 1e-5f);
    float2 g  = ((const float2*)gamma)[tid];
    float2 bb = ((const float2*)beta)[tid];
    short o2[2];
    o2[0] = f2bf((v.x - mu) * inv * g.x + bb.x);
    o2[1] = f2bf((v.y - mu) * inv * g.y + bb.y);
    *(unsigned int*)&xn[(size_t)row * DMODEL + tid * 2] = *(unsigned int*)o2;
}

// ---------------- bf16 MFMA GEMM (m97 structure: 128x128 tile, BK=32) ----------------
template<int MODE>
__global__ __launch_bounds__(256) void gemm_bf16(
    const short* __restrict__ A, const short* __restrict__ W,
    const float* __restrict__ b0, const float* __restrict__ b1, const float* __restrict__ b2,
    short* __restrict__ Oq, short* __restrict__ Ok, short* __restrict__ Ov,
    float* __restrict__ Of, const float* __restrict__ resid)
{
    __shared__ short As[128 * 32];
    __shared__ short Bs[128 * 32];
    const int K = 512;
    const int tid = threadIdx.x;
    const int lane = tid & 63, w = tid >> 6;
    const int m0 = blockIdx.y * 128, n0 = blockIdx.x * 128;
    const int wr = w >> 1, wc = w & 1;

    const int srow = (lane >> 2);
    const int scol = (lane & 3) * 8;
    int ga0 = m0 + (w * 2 + 0) * 16 + srow; if (ga0 > 7999) ga0 = 7999;
    int ga1 = m0 + (w * 2 + 1) * 16 + srow; if (ga1 > 7999) ga1 = 7999;
    const int gb0 = n0 + (w * 2 + 0) * 16 + srow;
    const int gb1 = n0 + (w * 2 + 1) * 16 + srow;

    f32x4 acc[4][4];
#pragma unroll
    for (int i = 0; i < 4; ++i)
#pragma unroll
        for (int j = 0; j < 4; ++j) acc[i][j] = (f32x4){0.f, 0.f, 0.f, 0.f};

    for (int k0 = 0; k0 < K; k0 += 32) {
        __syncthreads();
        gload_lds16(&A[(size_t)ga0 * K + k0 + scol], &As[(w * 2 + 0) * 512]);
        gload_lds16(&A[(size_t)ga1 * K + k0 + scol], &As[(w * 2 + 1) * 512]);
        gload_lds16(&W[(size_t)gb0 * K + k0 + scol], &Bs[(w * 2 + 0) * 512]);
        gload_lds16(&W[(size_t)gb1 * K + k0 + scol], &Bs[(w * 2 + 1) * 512]);
        __syncthreads();

        bf16x8 af[4], bf[4];
#pragma unroll
        for (int fi = 0; fi < 4; ++fi)
            af[fi] = *(bf16x8*)&As[(wr * 64 + fi * 16 + (lane & 15)) * 32 + (lane >> 4) * 8];
#pragma unroll
        for (int fj = 0; fj < 4; ++fj)
            bf[fj] = *(bf16x8*)&Bs[(wc * 64 + fj * 16 + (lane & 15)) * 32 + (lane >> 4) * 8];
#pragma unroll
        for (int fi = 0; fi < 4; ++fi)
#pragma unroll
            for (int fj = 0; fj < 4; ++fj)
                acc[fi][fj] = __builtin_amdgcn_mfma_f32_16x16x32_bf16(af[fi], bf[fj], acc[fi][fj], 0, 0, 0);
    }

#pragma unroll
    for (int fi = 0; fi < 4; ++fi) {
#pragma unroll
        for (int fj = 0; fj < 4; ++fj) {
#pragma unroll
            for (int r = 0; r < 4; ++r) {
                int m = m0 + wr * 64 + fi * 16 + (lane >> 4) * 4 + r;
                if (m >= 8000) continue;
                int n = n0 + wc * 64 + fj * 16 + (lane & 15);
                float val = acc[fi][fj][r];
                if (MODE == 0) {
                    int proj = n >> 9, rem = n & 511;
                    int h = rem >> 6, d = rem & 63;
                    float bias = proj == 0 ? b0[rem] * 0.125f : (proj == 1 ? b1[rem] : b2[rem]);
                    short* O = proj == 0 ? Oq : (proj == 1 ? Ok : Ov);
                    int bb = m / 1000, ii = m - bb * 1000;
                    O[((size_t)(bb * NHEAD + h) * LSEQ + ii) * DK + d] = f2bf(val + bias);
                } else {
                    Of[(size_t)m * DMODEL + n] = val + b0[n] + resid[(size_t)m * DMODEL + n];
                }
            }
        }
    }
}

// ---------------- Flash attention, bf16 MFMA, bf16 I/O ----------------
// Per-wave Pp window: wave w only needs diag band d in [48-16w, 128-16w)
// = 5 fd-blocks (fd = 3-w .. 7-w). Pos MFMA 16->10/jt, E loads 16->10/lane/jt,
// Pp [64][136]->[64][92]. LDS 39424 B -> 4 blocks/CU (grid exactly 4/CU).
__global__ __launch_bounds__(256, 4) void attn_mfma(
    const short* __restrict__ q, const short* __restrict__ k,
    const short* __restrict__ v, const short* __restrict__ E,
    short* __restrict__ ctx)
{
    __shared__ short QsPl[TI][72];   // Q tile, then P tile (wave-private rows)
    __shared__ short Kt[TJ][72];
    __shared__ short Vt[DK][72];     // V transposed: Vt[d][j]
    __shared__ short Pp[TI][92];     // per-wave 80-col pos window (92-pad: g-groups on disjoint banks)

    const int it = blockIdx.x, h = blockIdx.y, b = blockIdx.z;
    const int i0 = it * TI;
    const int tid = threadIdx.x;
    const int lane = tid & 63, w = tid >> 6;
    const int g = lane >> 4, c = lane & 15;

    const size_t base = (size_t)(b * NHEAD + h) * LSEQ * DK;

    // stage Q tile (bf16 direct copy, row-clamped)
#pragma unroll
    for (int rep = 0; rep < 2; ++rep) {
        int id = tid + rep * 256;
        int row = id >> 3, c0 = (id & 7) * 8;
        int gr = i0 + row; if (gr > LSEQ - 1) gr = LSEQ - 1;
        *(int4*)&QsPl[row][c0] = *(const int4*)&q[base + (size_t)gr * DK + c0];
    }
    __syncthreads();

    bf16x8 Aq0 = *(bf16x8*)&QsPl[w * 16 + c][g * 8];
    bf16x8 Aq1 = *(bf16x8*)&QsPl[w * 16 + c][32 + g * 8];

    float mrow[4], lrow[4];
    f32x4 acc[4];
#pragma unroll
    for (int r = 0; r < 4; ++r) { mrow[r] = -1e30f; lrow[r] = 0.f; }
#pragma unroll
    for (int fd = 0; fd < 4; ++fd) acc[fd] = (f32x4){0.f, 0.f, 0.f, 0.f};

    for (int jt = 0; jt < NJT; ++jt) {
        const int j0 = jt * TJ;
        const int d0 = j0 - i0 + (LSEQ - 1) - 63;
        __syncthreads();   // prev iteration LDS reads done; QsPl free at jt=0

        // ---- stage K tile ----
#pragma unroll
        for (int rep = 0; rep < 2; ++rep) {
            int id = tid + rep * 256;
            int row = id >> 3, c0 = (id & 7) * 8;
            int gr = j0 + row; if (gr > LSEQ - 1) gr = LSEQ - 1;
            *(int4*)&Kt[row][c0] = *(const int4*)&k[base + (size_t)gr * DK + c0];
        }
        // ---- stage V transposed, conflict-free writes ----
#pragma unroll
        for (int rep = 0; rep < 4; ++rep) {
            int id = tid + rep * 256;
            int j = ((id >> 8) << 4) | (id & 15);
            int dq = ((id >> 4) & 15) * 4;
            int gr = j0 + j; if (gr > LSEQ - 1) gr = LSEQ - 1;
            short t[4];
            *(int2*)t = *(const int2*)&v[base + (size_t)gr * DK + dq];
            Vt[dq + 0][j] = t[0];
            Vt[dq + 1][j] = t[1];
            Vt[dq + 2][j] = t[2];
            Vt[dq + 3][j] = t[3];
        }
        // ---- E window B-fragments, only this wave's 5 fd-blocks ----
        bf16x8 ef[5][2];
#pragma unroll
        for (int fdl = 0; fdl < 5; ++fdl) {
            int dd = d0 + (3 - w + fdl) * 16 + c;
            if (dd < 0) dd = 0;
            if (dd > 2 * LSEQ - 2) dd = 2 * LSEQ - 2;
            const short* erow = E + (size_t)dd * DK;
            ef[fdl][0] = *(const bf16x8*)&erow[g * 8];
            ef[fdl][1] = *(const bf16x8*)&erow[32 + g * 8];
        }
        __syncthreads();

        // ---- pos scores: wave-private 80-col window ----
#pragma unroll
        for (int fdl = 0; fdl < 5; ++fdl) {
            f32x4 pa = (f32x4){0.f, 0.f, 0.f, 0.f};
            pa = __builtin_amdgcn_mfma_f32_16x16x32_bf16(Aq0, ef[fdl][0], pa, 0, 0, 0);
            pa = __builtin_amdgcn_mfma_f32_16x16x32_bf16(Aq1, ef[fdl][1], pa, 0, 0, 0);
#pragma unroll
            for (int r = 0; r < 4; ++r)
                Pp[w * 16 + g * 4 + r][fdl * 16 + c] = f2bf(pa[r]);
        }

        // ---- QK^T ----
        f32x4 sf[4];
#pragma unroll
        for (int fj = 0; fj < 4; ++fj) {
            f32x4 s4 = (f32x4){0.f, 0.f, 0.f, 0.f};
            bf16x8 k0v = *(bf16x8*)&Kt[fj * 16 + c][g * 8];
            bf16x8 k1v = *(bf16x8*)&Kt[fj * 16 + c][32 + g * 8];
            s4 = __builtin_amdgcn_mfma_f32_16x16x32_bf16(Aq0, k0v, s4, 0, 0, 0);
            s4 = __builtin_amdgcn_mfma_f32_16x16x32_bf16(Aq1, k1v, s4, 0, 0, 0);
            sf[fj] = s4;
        }

        // ---- add pos (diag gather; local col = fj*16+15+c-(g*4+r)), mask, softmax ----
        float sv[4][4], pm[4];
#pragma unroll
        for (int r = 0; r < 4; ++r) pm[r] = -1e30f;
#pragma unroll
        for (int fj = 0; fj < 4; ++fj) {
            int jl = fj * 16 + c;
            bool valid = (j0 + jl) < LSEQ;
#pragma unroll
            for (int r = 0; r < 4; ++r) {
                int ilt = w * 16 + g * 4 + r;
                int dl = fj * 16 + 15 + c - (g * 4 + r);   // in [0,79)
                float x = sf[fj][r] + bf2f(Pp[ilt][dl]);
                if (!valid) x = -1e30f;
                sv[fj][r] = x;
                pm[r] = fmaxf(pm[r], x);
            }
        }
#pragma unroll
        for (int r = 0; r < 4; ++r) {
            float vv = pm[r];
            vv = fmaxf(vv, __shfl_xor(vv, 1));
            vv = fmaxf(vv, __shfl_xor(vv, 2));
            vv = fmaxf(vv, __shfl_xor(vv, 4));
            vv = fmaxf(vv, __shfl_xor(vv, 8));
            pm[r] = vv;
        }
        float psum[4];
#pragma unroll
        for (int r = 0; r < 4; ++r) {
            float mn = fmaxf(mrow[r], pm[r]);
            float sc = __expf(mrow[r] - mn);
            mrow[r] = mn;
            lrow[r] *= sc;
#pragma unroll
            for (int fd = 0; fd < 4; ++fd) acc[fd][r] *= sc;
            psum[r] = 0.f;
        }
#pragma unroll
        for (int fj = 0; fj < 4; ++fj) {
            int jl = fj * 16 + c;
#pragma unroll
            for (int r = 0; r < 4; ++r) {
                float p = __expf(sv[fj][r] - mrow[r]);
                psum[r] += p;
                QsPl[w * 16 + g * 4 + r][jl] = f2bf(p);
            }
        }
#pragma unroll
        for (int r = 0; r < 4; ++r) {
            float vv = psum[r];
            vv += __shfl_xor(vv, 1);
            vv += __shfl_xor(vv, 2);
            vv += __shfl_xor(vv, 4);
            vv += __shfl_xor(vv, 8);
            lrow[r] += vv;
        }

        // ---- PV ----
#pragma unroll
        for (int ks = 0; ks < 2; ++ks) {
            bf16x8 ap = *(bf16x8*)&QsPl[w * 16 + c][ks * 32 + g * 8];
#pragma unroll
            for (int fd = 0; fd < 4; ++fd) {
                bf16x8 bv2 = *(bf16x8*)&Vt[fd * 16 + c][ks * 32 + g * 8];
                acc[fd] = __builtin_amdgcn_mfma_f32_16x16x32_bf16(ap, bv2, acc[fd], 0, 0, 0);
            }
        }
    }

    // ---- epilogue: normalize + store ctx bf16 (B, L, D) ----
#pragma unroll
    for (int r = 0; r < 4; ++r) {
        int ig = i0 + w * 16 + g * 4 + r;
        if (ig < LSEQ) {
            float inv = 1.0f / lrow[r];
#pragma unroll
            for (int fd = 0; fd < 4; ++fd)
                ctx[((size_t)(b * LSEQ + ig)) * DMODEL + h * DK + fd * 16 + c] =
                    f2bf(acc[fd][r] * inv);
        }
    }
}

extern "C" void kernel_launch(void* const* d_in, const int* in_sizes, int n_in,
                              void* d_out, int out_size, void* d_ws, size_t ws_size,
                              hipStream_t stream)
{
    const float* x     = (const float*)d_in[0];
    const float* Wq    = (const float*)d_in[1];
    const float* bq    = (const float*)d_in[2];
    const float* Wk    = (const float*)d_in[3];
    const float* bk    = (const float*)d_in[4];
    const float* Wv    = (const float*)d_in[5];
    const float* bv    = (const float*)d_in[6];
    const float* Wo    = (const float*)d_in[7];
    const float* bo    = (const float*)d_in[8];
    const float* E     = (const float*)d_in[9];
    const float* gamma = (const float*)d_in[10];
    const float* beta  = (const float*)d_in[11];
    float* out = (float*)d_out;

    const size_t nTok = 8 * LSEQ;               // 8000
    const size_t nBLD = nTok * DMODEL;          // 4,096,000 elems
    short* xn_bf   = (short*)d_ws;
    short* qb      = xn_bf + nBLD;
    short* kb      = qb + nBLD;
    short* vb      = kb + nBLD;
    short* ctx_bf  = vb + nBLD;
    short* Wqkv_bf = ctx_bf + nBLD;
    short* Wo_bf   = Wqkv_bf + 1536 * 512;
    short* E_bf    = Wo_bf + 512 * 512;

    convert_kernel<<<1149, 256, 0, stream>>>(Wq, Wk, Wv, Wo, E, Wqkv_bf, Wo_bf, E_bf);
    ln_kernel<<<(int)nTok, 256, 0, stream>>>(x, gamma, beta, xn_bf);
    gemm_bf16<0><<<dim3(12, 63), 256, 0, stream>>>(
        xn_bf, Wqkv_bf, bq, bk, bv, qb, kb, vb, nullptr, nullptr);
    attn_mfma<<<dim3((LSEQ + TI - 1) / TI, NHEAD, 8), 256, 0, stream>>>(
        qb, kb, vb, E_bf, ctx_bf);
    gemm_bf16<1><<<dim3(4, 63), 256, 0, stream>>>(
        ctx_bf, Wo_bf, bo, nullptr, nullptr, nullptr, nullptr, nullptr, out, x);
}